// Round 10
// baseline (335.223 us; speedup 1.0000x reference)
//
#include <hip/hip_runtime.h>
#include <hip/hip_bf16.h>

#define BB 8
#define CC 128
#define NN 4096  // H*W
#define LOG2E 1.44269504088896340736f

typedef __attribute__((ext_vector_type(8))) short bf16x8;   // 8 bf16 = 4 VGPRs
typedef __attribute__((ext_vector_type(16))) float f32x16;

static __device__ __forceinline__ unsigned short f2bfu(float f) {
  unsigned int x = __float_as_uint(f);
  x += 0x7fffu + ((x >> 16) & 1u);
  return (unsigned short)(x >> 16);
}
static __device__ __forceinline__ unsigned int packbf(float a, float b) {
  return (unsigned int)f2bfu(a) | ((unsigned int)f2bfu(b) << 16);
}
static __device__ __forceinline__ float bfu2f(unsigned short u) {
  return __uint_as_float((unsigned int)u << 16);
}
// raw v_exp_f32 (2^x). Domain bounded (|s|<90) -> no range fixup needed.
static __device__ __forceinline__ float fexp2(float x) {
  return __builtin_amdgcn_exp2f(x);
}
static __device__ __forceinline__ f32x16 zero16() {
  f32x16 z;
#pragma unroll
  for (int i = 0; i < 16; ++i) z[i] = 0.f;
  return z;
}
union Frag { int i[4]; unsigned int u[4]; bf16x8 v; };

// RNE pack of two f32 -> two bf16 in one dword (lo = a). No builtin on gfx950.
static __device__ __forceinline__ unsigned int cvtpk(float a, float b) {
  unsigned int r;
  asm("v_cvt_pk_bf16_f32 %0, %1, %2" : "=v"(r) : "v"(a), "v"(b));
  return r;
}
// Swap d[lanes 32..63] <-> s[lanes 0..31]; both results used.
static __device__ __forceinline__ void pl32swap(unsigned int& d, unsigned int& s) {
  asm volatile("v_permlane32_swap_b32 %0, %1" : "+v"(d), "+v"(s));
}

// async global->LDS, 16B/lane; LDS dest = wave-uniform base + lane*16.
#define GLD16(gp, lp)                                                     \
  __builtin_amdgcn_global_load_lds(                                       \
      (const __attribute__((address_space(1))) unsigned int*)(gp),        \
      (__attribute__((address_space(3))) unsigned int*)(lp), 16, 0, 0)

// C/D row pattern for 32x32 MFMA: row = (rg&3) + 8*(rg>>2) + 4*q2
#define ROWPAT(rg, q2) (((rg) & 3) + 8 * ((rg) >> 2) + 4 * (q2))

// Build 2 PV A-frags (m-local 0..15 / 16..31) from a 32-row S' acc.
// lane holds p[rg] = P[m = ROWPAT(rg,q2)][n = cm]; A-frag lo/hi: lane needs
// P[m = 16*ks + 8*q2 + j][n = cm], j = 0..7. Verified recipe (R0/R1 kernels).
static __device__ __forceinline__ void make_pa(const f32x16& s, Frag& lo, Frag& hi) {
  float p[16];
#pragma unroll
  for (int rg = 0; rg < 16; ++rg) p[rg] = fexp2(s[rg]);
  unsigned int a0 = cvtpk(p[0], p[1]),   b0 = cvtpk(p[4], p[5]);
  pl32swap(a0, b0);
  unsigned int a1 = cvtpk(p[2], p[3]),   b1 = cvtpk(p[6], p[7]);
  pl32swap(a1, b1);
  lo.u[0] = a0; lo.u[1] = a1; lo.u[2] = b0; lo.u[3] = b1;
  unsigned int c0 = cvtpk(p[8], p[9]),   d0 = cvtpk(p[12], p[13]);
  pl32swap(c0, d0);
  unsigned int c1 = cvtpk(p[10], p[11]), d1 = cvtpk(p[14], p[15]);
  pl32swap(c1, d1);
  hi.u[0] = c0; hi.u[1] = c1; hi.u[2] = d0; hi.u[3] = d1;
}

// ---------------------------------------------------------------------------
// Dual conv1x1 input stage via MFMA. blockIdx.z: 0 = theta(ref) -> Xnc (scaled
// by log2e) + Xcn; 1 = phi(cur) -> Ync only.
// ---------------------------------------------------------------------------
__global__ __launch_bounds__(256, 4) void nl_conv2m(
    const float* __restrict__ ref, const float* __restrict__ theta_w,
    const float* __restrict__ theta_b,
    const float* __restrict__ cur, const float* __restrict__ phi_w,
    const float* __restrict__ phi_b,
    unsigned short* __restrict__ Xnc, unsigned short* __restrict__ Xcn,
    unsigned short* __restrict__ Ync)
{
  __shared__ float sm[64 * 129];  // phase1: [c=128][j=64]; phase2: [j=64][o] stride 129
  const int z  = blockIdx.z;
  const float* in   = z ? cur : ref;
  const float* w    = z ? phi_w : theta_w;
  const float* bias = z ? phi_b : theta_b;
  unsigned short* out_nc = z ? Ync : Xnc;
  unsigned short* out_cn = z ? nullptr : Xcn;
  const float nc_scale = z ? 1.0f : LOG2E;

  const int b  = blockIdx.y;
  const int n0 = blockIdx.x * 64;
  const int t  = threadIdx.x;
  const int wave = t >> 6, lane = t & 63, q2 = lane >> 5, cm = lane & 31;

  // stage X fp32: [c][j], coalesced float2
#pragma unroll
  for (int k = 0; k < 16; ++k) {
    int flat = t + 256 * k;          // 4096 float2 slots
    int c = flat >> 5, jp = flat & 31;
    float2 v = *(const float2*)&in[(size_t)b * CC * NN + (size_t)c * NN + n0 + jp * 2];
    sm[c * 64 + jp * 2]     = v.x;
    sm[c * 64 + jp * 2 + 1] = v.y;
  }

  // A-frags: W rows o = wave*32 + cm, fp32 -> bf16
  bf16x8 wf[8];
  const int o0 = wave * 32 + cm;
#pragma unroll
  for (int k = 0; k < 8; ++k) {
    const float* wp = &w[o0 * CC + k * 16 + q2 * 8];
    float4 w0 = *(const float4*)wp, w1 = *(const float4*)(wp + 4);
    Frag f;
    f.u[0] = packbf(w0.x, w0.y); f.u[1] = packbf(w0.z, w0.w);
    f.u[2] = packbf(w1.x, w1.y); f.u[3] = packbf(w1.z, w1.w);
    wf[k] = f.v;
  }
  __syncthreads();

  // MFMA: per wave 2 j-tiles of 32; B-frag = 8 x ds_read_b32 (conflict-free) + cvtpk
  f32x16 acc[2];
  acc[0] = zero16(); acc[1] = zero16();
#pragma unroll
  for (int k = 0; k < 8; ++k) {
#pragma unroll
    for (int jt = 0; jt < 2; ++jt) {
      int base = (k * 16 + q2 * 8) * 64 + jt * 32 + cm;
      Frag xb;
      xb.u[0] = cvtpk(sm[base],       sm[base + 64]);
      xb.u[1] = cvtpk(sm[base + 128], sm[base + 192]);
      xb.u[2] = cvtpk(sm[base + 256], sm[base + 320]);
      xb.u[3] = cvtpk(sm[base + 384], sm[base + 448]);
      acc[jt] = __builtin_amdgcn_mfma_f32_32x32x16_bf16(wf[k], xb.v, acc[jt], 0, 0, 0);
    }
  }
  __syncthreads();  // all B-frag reads done; sm reusable

  // acc -> sm[j][129 o-stride] (+bias); D: col=j=jt*32+cm, row=o=wave*32+ROWPAT
#pragma unroll
  for (int jt = 0; jt < 2; ++jt)
#pragma unroll
    for (int rg = 0; rg < 16; ++rg) {
      int o = wave * 32 + ROWPAT(rg, q2);
      sm[(jt * 32 + cm) * 129 + o] = acc[jt][rg] + bias[o];
    }
  __syncthreads();

  // output stages (verbatim from proven conv2)
#pragma unroll
  for (int k = 0; k < 16; ++k) {
    int flat = t + 256 * k;           // [N][C] bf16 pairs
    int cp = flat & 63, jj = flat >> 6;
    float f0 = sm[jj * 129 + cp * 2] * nc_scale;
    float f1 = sm[jj * 129 + cp * 2 + 1] * nc_scale;
    *(unsigned int*)(out_nc + ((size_t)b * NN + n0 + jj) * CC + cp * 2) = packbf(f0, f1);
  }
  if (out_cn) {
#pragma unroll
    for (int k = 0; k < 16; ++k) {
      int flat = t + 256 * k;         // [C][N] bf16 n-pairs, unscaled
      int jp = flat & 31, c = flat >> 5;
      float f0 = sm[(jp * 2) * 129 + c], f1 = sm[(jp * 2 + 1) * 129 + c];
      *(unsigned int*)(out_cn + ((size_t)b * CC + c) * NN + n0 + jp * 2) = packbf(f0, f1);
    }
  }
}

// ---------------------------------------------------------------------------
// Pass 1: L[m] = sum_n exp2(s[n,m]) over an n-quarter. Double-buffered, 4
// blocks/CU. Xt swizzle upgraded to ^(row&15): rows are 256B (= 0 mod 32
// banks); &7 left lanes 8 apart on the same banks (4-way conflict). &15 over
// the 16-chunk space makes same-chunk pairs 16 apart -> 2-way (free, m136).
// ---------------------------------------------------------------------------
__global__ __launch_bounds__(256, 4) void nl_stats4(
    const unsigned short* __restrict__ Xnc, const unsigned short* __restrict__ Ync,
    float* __restrict__ Lpart)
{
  __shared__ unsigned short Xt[2][64 * 128];  // 2 x 16 KB, [n][c], chunk ^= (row&15)
  __shared__ float sL[2][2][2][32];           // [nh][mq][ct][cm]
  const int b = blockIdx.z, nq = blockIdx.y, mstrip = blockIdx.x;
  const int t = threadIdx.x;
  const int wave = t >> 6, lane = t & 63, q2 = lane >> 5, cm = lane & 31;
  const int mq = wave & 1, nh = wave >> 1;
  const int m0w = mstrip * 128 + mq * 64;

  bf16x8 bf[2][8];  // B[k=c][col=m] for 2 col-tiles of 32 m
#pragma unroll
  for (int ct = 0; ct < 2; ++ct)
#pragma unroll
    for (int k = 0; k < 8; ++k)
      bf[ct][k] = *(const bf16x8*)(Ync + ((size_t)b * NN + m0w + ct * 32 + cm) * CC + k * 16 + q2 * 8);

  // prologue: stage tile 0
  {
    const int n0 = nq * 1024;
#pragma unroll
    for (int i = 0; i < 4; ++i) {
      int slot = i * 256 + t;
      int row = slot >> 4, g = (slot & 15) ^ (row & 15);
      GLD16(Xnc + ((size_t)b * NN + n0 + row) * CC + g * 8, &Xt[0][0] + i * 2048 + wave * 512);
    }
  }

  float runL[2] = {0.f, 0.f};
#pragma unroll 2
  for (int nt = 0; nt < 16; ++nt) {
    __syncthreads();  // staging(nt) complete; buf^1 free (compute nt-1 done)
    if (nt < 15) {
      const int n0 = nq * 1024 + (nt + 1) * 64;
      unsigned short* dst = &Xt[(nt + 1) & 1][0];
#pragma unroll
      for (int i = 0; i < 4; ++i) {
        int slot = i * 256 + t;
        int row = slot >> 4, g = (slot & 15) ^ (row & 15);
        GLD16(Xnc + ((size_t)b * NN + n0 + row) * CC + g * 8, dst + i * 2048 + wave * 512);
      }
    }
    const unsigned short* src = &Xt[nt & 1][0];
    f32x16 acc0 = zero16(), acc1 = zero16();
#pragma unroll
    for (int k = 0; k < 8; ++k) {
      // read row = nh*32+cm -> row&15 = cm&15
      bf16x8 av = *(const bf16x8*)&src[(nh * 32 + cm) * 128 + (((k << 1) | q2) ^ (cm & 15)) * 8];
      acc0 = __builtin_amdgcn_mfma_f32_32x32x16_bf16(av, bf[0][k], acc0, 0, 0, 0);
      acc1 = __builtin_amdgcn_mfma_f32_32x32x16_bf16(av, bf[1][k], acc1, 0, 0, 0);
    }
#pragma unroll
    for (int rg = 0; rg < 16; ++rg) {
      runL[0] += fexp2(acc0[rg]);
      runL[1] += fexp2(acc1[rg]);
    }
  }
#pragma unroll
  for (int ct = 0; ct < 2; ++ct) runL[ct] += __shfl_xor(runL[ct], 32);
  if (q2 == 0) {
    sL[nh][mq][0][cm] = runL[0];
    sL[nh][mq][1][cm] = runL[1];
  }
  __syncthreads();
  if (t < 128) {
    int mq2 = t >> 6, ct2 = (t >> 5) & 1, cm2 = t & 31;
    float L = sL[0][mq2][ct2][cm2] + sL[1][mq2][ct2][cm2];
    Lpart[((size_t)nq * BB + b) * NN + mstrip * 128 + mq2 * 64 + ct2 * 32 + cm2] = L;
  }
}

// ---------------------------------------------------------------------------
// Fused mergeL + xscale: per (b, 64-m chunk): iL[m] = 1/sum(4 Lpart) in LDS,
// then Xcn[c][m] *= iL[m] in-place for all 128 c. Grid 512 = 2 blocks/CU.
// ---------------------------------------------------------------------------
__global__ __launch_bounds__(256) void nl_scalev(
    const float* __restrict__ Lp, unsigned short* __restrict__ Xcn)
{
  __shared__ float iL[64];
  const int b = blockIdx.y, mc = blockIdx.x;
  const int t = threadIdx.x;
  const int m0 = mc * 64;
  if (t < 64) {
    size_t idx = (size_t)b * NN + m0 + t;
    float L = Lp[idx] + Lp[(size_t)BB * NN + idx] + Lp[(size_t)2 * BB * NN + idx] +
              Lp[(size_t)3 * BB * NN + idx];
    iL[t] = 1.0f / L;
  }
  __syncthreads();
#pragma unroll
  for (int r = 0; r < 4; ++r) {
    int idx = r * 256 + t;            // 1024 groups of 8 bf16 (128 c x 8 mg)
    int c = idx >> 3, mg = idx & 7;
    size_t base = ((size_t)b * CC + c) * NN + m0 + mg * 8;
    Frag x; x.v = *(const bf16x8*)(Xcn + base);
    const float* il = &iL[mg * 8];
    Frag o;
    o.u[0] = packbf(bfu2f(x.u[0] & 0xffff) * il[0], bfu2f(x.u[0] >> 16) * il[1]);
    o.u[1] = packbf(bfu2f(x.u[1] & 0xffff) * il[2], bfu2f(x.u[1] >> 16) * il[3]);
    o.u[2] = packbf(bfu2f(x.u[2] & 0xffff) * il[4], bfu2f(x.u[2] >> 16) * il[5]);
    o.u[3] = packbf(bfu2f(x.u[3] & 0xffff) * il[6], bfu2f(x.u[3] >> 16) * il[7]);
    *(bf16x8*)(Xcn + base) = o.v;
  }
}

// ---------------------------------------------------------------------------
// Pass 2 (paired-m, halved LDS reads — R2 structure retried in the LDS-bound
// regime): Zpart[n,c] = sum_m exp2(s[n,m])*Xsc[m,c] over an m-half.
// Wave = (npair = wave>>1 owns 64 n, msub = wave&1 owns 32 of the 64-m tile).
// Every LDS frag feeds 2 MFMAs: 8 av + 8 xv reads per 32 MFMA (e2 had 32).
// Yt swizzle ^(m&15) kills the av 4-way bank conflict (rows 256B). Xv keeps
// ^(c&7) (128B rows, 8 chunks — 4-way inherent, only 8 reads/iter).
// Cross-msub z reduction once at kernel end through the 64 KB LDS; bf16 out.
// ---------------------------------------------------------------------------
__global__ __launch_bounds__(256, 2) void nl_pass2f2(
    const unsigned short* __restrict__ Xnc, const unsigned short* __restrict__ Ync,
    const unsigned short* __restrict__ Xsc,
    unsigned short* __restrict__ Zpart)
{
  // SB[buf][0..8191] = Y tile [m64][c128] (chunk ^= m&15); [8192..16383] =
  // X tile [c128][m64] (chunk ^= c&7). Reused as f32 z-exchange at end.
  __shared__ unsigned short SB[2][16384];
  const int b = blockIdx.z, mhalf = blockIdx.y, nstrip = blockIdx.x;
  const int t = threadIdx.x;
  const int wave = t >> 6, lane = t & 63, q2 = lane >> 5, cm = lane & 31;
  const int npair = wave >> 1, msub = wave & 1;

  // X B-frags pinned: n cols = nstrip*128 + npair*64 + g*32 + cm (whole kernel)
  bf16x8 af[2][8];
#pragma unroll
  for (int g = 0; g < 2; ++g)
#pragma unroll
    for (int k = 0; k < 8; ++k)
      af[g][k] = *(const bf16x8*)(Xnc +
          ((size_t)b * NN + nstrip * 128 + npair * 64 + g * 32 + cm) * CC + k * 16 + q2 * 8);

  f32x16 z[2][4];
#pragma unroll
  for (int g = 0; g < 2; ++g)
#pragma unroll
    for (int ct = 0; ct < 4; ++ct) z[g][ct] = zero16();

#define STAGEF(DSTBUF, M0G)                                                    \
  do {                                                                         \
    unsigned short* Yd = &SB[DSTBUF][0];                                       \
    unsigned short* Xd = &SB[DSTBUF][8192];                                    \
    _Pragma("unroll")                                                          \
    for (int i = 0; i < 4; ++i) {                                              \
      int slot = i * 256 + t;                                                  \
      int row = slot >> 4, g = (slot & 15) ^ (row & 15);                       \
      GLD16(Ync + ((size_t)b * NN + (M0G) + row) * CC + g * 8,                 \
            Yd + i * 2048 + wave * 512);                                       \
    }                                                                          \
    _Pragma("unroll")                                                          \
    for (int i = 0; i < 4; ++i) {                                              \
      int slot = i * 256 + t;                                                  \
      int row = slot >> 3, g = (slot & 7) ^ (row & 7);                         \
      GLD16(Xsc + ((size_t)b * CC + row) * NN + (M0G) + g * 8,                 \
            Xd + i * 2048 + wave * 512);                                       \
    }                                                                          \
  } while (0)

  // prologue: stage tile 0
  STAGEF(0, mhalf * 2048);

#define PF_ITER(BUF, MT)                                                       \
  do {                                                                         \
    __syncthreads();                                                           \
    if ((MT) < 31) STAGEF((BUF) ^ 1, mhalf * 2048 + ((MT) + 1) * 64);          \
    const unsigned short* Ys = &SB[BUF][0];                                    \
    f32x16 s0 = zero16(), s1 = zero16();                                       \
    __builtin_amdgcn_s_setprio(1);                                             \
    _Pragma("unroll")                                                          \
    for (int k = 0; k < 8; ++k) {                                              \
      const int ch = (((k << 1) | q2) ^ (cm & 15)) * 8;                        \
      bf16x8 av = *(const bf16x8*)&Ys[(msub * 32 + cm) * 128 + ch];            \
      s0 = __builtin_amdgcn_mfma_f32_32x32x16_bf16(av, af[0][k], s0, 0, 0, 0); \
      s1 = __builtin_amdgcn_mfma_f32_32x32x16_bf16(av, af[1][k], s1, 0, 0, 0); \
    }                                                                          \
    __builtin_amdgcn_s_setprio(0);                                             \
    Frag pa[2][2];                                                             \
    make_pa(s0, pa[0][0], pa[0][1]);                                           \
    make_pa(s1, pa[1][0], pa[1][1]);                                           \
    const unsigned short* Xs = &SB[BUF][8192];                                 \
    __builtin_amdgcn_s_setprio(1);                                             \
    _Pragma("unroll")                                                          \
    for (int ksl = 0; ksl < 2; ++ksl) {                                        \
      const int ksg = msub * 2 + ksl;                                          \
      const int ch = (((ksg << 1) | q2) ^ (cm & 7)) * 8;                       \
      _Pragma("unroll")                                                        \
      for (int ct = 0; ct < 4; ++ct) {                                         \
        bf16x8 xv = *(const bf16x8*)&Xs[(ct * 32 + cm) * 64 + ch];             \
        z[0][ct] = __builtin_amdgcn_mfma_f32_32x32x16_bf16(pa[0][ksl].v, xv, z[0][ct], 0, 0, 0); \
        z[1][ct] = __builtin_amdgcn_mfma_f32_32x32x16_bf16(pa[1][ksl].v, xv, z[1][ct], 0, 0, 0); \
      }                                                                        \
    }                                                                          \
    __builtin_amdgcn_s_setprio(0);                                             \
  } while (0)

  for (int mt2 = 0; mt2 < 16; ++mt2) {
    PF_ITER(0, mt2 * 2);
    PF_ITER(1, mt2 * 2 + 1);
  }
#undef PF_ITER
#undef STAGEF

  // ---- cross-pair (m-sub) z reduction through LDS, then bf16 epilogue ----
  __syncthreads();  // all tile compute done; SB free
  float* zl = (float*)&SB[0][0] + npair * 8192;  // 32 KB per npair
  if (msub == 1) {
#pragma unroll
    for (int g = 0; g < 2; ++g)
#pragma unroll
      for (int ct = 0; ct < 4; ++ct)
#pragma unroll
        for (int rg = 0; rg < 16; ++rg)
          zl[(g * 32 + ROWPAT(rg, q2)) * 128 + ct * 32 + cm] = z[g][ct][rg];
  }
  __syncthreads();
  if (msub == 0) {
    unsigned short* Zp = Zpart + ((size_t)mhalf * BB + b) * NN * CC;
#pragma unroll
    for (int g = 0; g < 2; ++g)
#pragma unroll
      for (int ct = 0; ct < 4; ++ct)
#pragma unroll
        for (int rg = 0; rg < 16; ++rg) {
          int nl = g * 32 + ROWPAT(rg, q2);
          int n = nstrip * 128 + npair * 64 + nl;
          Zp[(size_t)n * CC + ct * 32 + cm] =
              f2bfu(z[g][ct][rg] + zl[nl * 128 + ct * 32 + cm]);
        }
  }
}

// ---------------------------------------------------------------------------
// Final conv1x1 via MFMA with fused Zpart reduction. 64-n strips (grid 512 =
// 2 blocks/CU) for latency hiding on the Zpart reads.
// ---------------------------------------------------------------------------
__global__ __launch_bounds__(256) void nl_convw2(
    const unsigned short* __restrict__ Zpart, const float* __restrict__ w,
    const float* __restrict__ bias, float* __restrict__ out)
{
  __shared__ unsigned short Zt[64 * 128];  // 16 KB, [n][c], chunk ^= (n&7)
  const int b = blockIdx.y, nstrip = blockIdx.x;  // 64 strips of 64 n
  const int t = threadIdx.x;
  const int wave = t >> 6, lane = t & 63, q2 = lane >> 5, cm = lane & 31;
  const int oh = wave & 1, nh2 = wave >> 1;       // o-half 64, n-half 32

  const unsigned short* Z0 = Zpart + ((size_t)b * NN + nstrip * 64) * CC;
  const unsigned short* Z1 = Z0 + (size_t)BB * NN * CC;
#pragma unroll
  for (int i = 0; i < 4; ++i) {
    int slot = i * 256 + t;
    int row = slot >> 4, g = slot & 15;
    size_t off = (size_t)row * CC + g * 8;
    Frag a, c2, o;
    a.v  = *(const bf16x8*)(Z0 + off);
    c2.v = *(const bf16x8*)(Z1 + off);
#pragma unroll
    for (int w2 = 0; w2 < 4; ++w2) {
      float lo = bfu2f((unsigned short)(a.u[w2] & 0xffff)) +
                 bfu2f((unsigned short)(c2.u[w2] & 0xffff));
      float hi = bfu2f((unsigned short)(a.u[w2] >> 16)) +
                 bfu2f((unsigned short)(c2.u[w2] >> 16));
      o.u[w2] = packbf(lo, hi);
    }
    *(bf16x8*)&Zt[row * 128 + ((g ^ (row & 7)) * 8)] = o.v;
  }

  // A-frags: W rows o = oh*64 + s2*32 + cm, fp32 -> bf16
  bf16x8 wf[2][8];
#pragma unroll
  for (int s2 = 0; s2 < 2; ++s2)
#pragma unroll
    for (int k = 0; k < 8; ++k) {
      const float* wp = &w[(oh * 64 + s2 * 32 + cm) * CC + k * 16 + q2 * 8];
      float4 w0 = *(const float4*)wp, w1 = *(const float4*)(wp + 4);
      Frag f;
      f.u[0] = packbf(w0.x, w0.y); f.u[1] = packbf(w0.z, w0.w);
      f.u[2] = packbf(w1.x, w1.y); f.u[3] = packbf(w1.z, w1.w);
      wf[s2][k] = f.v;
    }
  __syncthreads();

  f32x16 z[2];
  z[0] = zero16(); z[1] = zero16();
#pragma unroll
  for (int k = 0; k < 8; ++k) {
    bf16x8 bv = *(const bf16x8*)&Zt[(nh2 * 32 + cm) * 128 + (((k << 1) | q2) ^ (cm & 7)) * 8];
#pragma unroll
    for (int i = 0; i < 2; ++i)
      z[i] = __builtin_amdgcn_mfma_f32_32x32x16_bf16(wf[i][k], bv, z[i], 0, 0, 0);
  }

#pragma unroll
  for (int i = 0; i < 2; ++i)
#pragma unroll
    for (int rg = 0; rg < 16; ++rg) {
      int o = oh * 64 + i * 32 + ROWPAT(rg, q2);
      int n = nstrip * 64 + nh2 * 32 + cm;
      out[(size_t)b * CC * NN + (size_t)o * NN + n] = z[i][rg] + bias[o];
    }
}

// ---------------------------------------------------------------------------
extern "C" void kernel_launch(void* const* d_in, const int* in_sizes, int n_in,
                              void* d_out, int out_size, void* d_ws, size_t ws_size,
                              hipStream_t stream) {
  const float* cur     = (const float*)d_in[0];
  const float* ref     = (const float*)d_in[1];
  const float* theta_w = (const float*)d_in[2];
  const float* theta_b = (const float*)d_in[3];
  const float* phi_w   = (const float*)d_in[4];
  const float* phi_b   = (const float*)d_in[5];
  const float* Ww      = (const float*)d_in[6];
  const float* Wb      = (const float*)d_in[7];
  float* out = (float*)d_out;

  // ws: Xnc|Ync|Xcn bf16 (8MB ea) | Lpart 4*BB*NN f32 (0.5MB) | Zpart 2*BB*NN*CC bf16 (16MB)
  unsigned short* Xnc = (unsigned short*)d_ws;         // scaled by log2e
  unsigned short* Ync = Xnc + (size_t)BB * NN * CC;
  unsigned short* Xcn = Ync + (size_t)BB * NN * CC;    // becomes Xsc in-place
  float* Lpart = (float*)(Xcn + (size_t)BB * NN * CC);
  unsigned short* Zpart = (unsigned short*)(Lpart + (size_t)4 * BB * NN);

  dim3 blk(256);
  nl_conv2m  <<<dim3(64, BB, 2), blk, 0, stream>>>(ref, theta_w, theta_b,
                                                   cur, phi_w, phi_b, Xnc, Xcn, Ync);
  nl_stats4  <<<dim3(32, 4, BB), blk, 0, stream>>>(Xnc, Ync, Lpart);
  nl_scalev  <<<dim3(64, BB), blk, 0, stream>>>(Lpart, Xcn);
  nl_pass2f2 <<<dim3(32, 2, BB), blk, 0, stream>>>(Xnc, Ync, Xcn, Zpart);
  nl_convw2  <<<dim3(64, BB), blk, 0, stream>>>(Zpart, Ww, Wb, out);
}

// Round 11
// 233.307 us; speedup vs baseline: 1.4368x; 1.4368x over previous
//
#include <hip/hip_runtime.h>
#include <hip/hip_bf16.h>

#define BB 8
#define CC 128
#define NN 4096  // H*W
#define LOG2E 1.44269504088896340736f

typedef __attribute__((ext_vector_type(8))) short bf16x8;   // 8 bf16 = 4 VGPRs
typedef __attribute__((ext_vector_type(16))) float f32x16;

static __device__ __forceinline__ unsigned short f2bfu(float f) {
  unsigned int x = __float_as_uint(f);
  x += 0x7fffu + ((x >> 16) & 1u);
  return (unsigned short)(x >> 16);
}
static __device__ __forceinline__ unsigned int packbf(float a, float b) {
  return (unsigned int)f2bfu(a) | ((unsigned int)f2bfu(b) << 16);
}
static __device__ __forceinline__ float bfu2f(unsigned short u) {
  return __uint_as_float((unsigned int)u << 16);
}
// raw v_exp_f32 (2^x). Domain bounded (|s|<90) -> no range fixup needed.
static __device__ __forceinline__ float fexp2(float x) {
  return __builtin_amdgcn_exp2f(x);
}
static __device__ __forceinline__ f32x16 zero16() {
  f32x16 z;
#pragma unroll
  for (int i = 0; i < 16; ++i) z[i] = 0.f;
  return z;
}
union Frag { int i[4]; unsigned int u[4]; bf16x8 v; };

// RNE pack of two f32 -> two bf16 in one dword (lo = a). No builtin on gfx950.
static __device__ __forceinline__ unsigned int cvtpk(float a, float b) {
  unsigned int r;
  asm("v_cvt_pk_bf16_f32 %0, %1, %2" : "=v"(r) : "v"(a), "v"(b));
  return r;
}
// Swap d[lanes 32..63] <-> s[lanes 0..31]; both results used.
static __device__ __forceinline__ void pl32swap(unsigned int& d, unsigned int& s) {
  asm volatile("v_permlane32_swap_b32 %0, %1" : "+v"(d), "+v"(s));
}

// async global->LDS, 16B/lane; LDS dest = wave-uniform base + lane*16.
#define GLD16(gp, lp)                                                     \
  __builtin_amdgcn_global_load_lds(                                       \
      (const __attribute__((address_space(1))) unsigned int*)(gp),        \
      (__attribute__((address_space(3))) unsigned int*)(lp), 16, 0, 0)

// C/D row pattern for 32x32 MFMA: row = (rg&3) + 8*(rg>>2) + 4*q2
#define ROWPAT(rg, q2) (((rg) & 3) + 8 * ((rg) >> 2) + 4 * (q2))

// Build 2 PV A-frags (m-local 0..15 / 16..31) from a 32-row S' acc.
// lane holds p[rg] = P[m = ROWPAT(rg,q2)][n = cm]; A-frag lo/hi: lane needs
// P[m = 16*ks + 8*q2 + j][n = cm], j = 0..7. Verified recipe (R0/R1 kernels).
static __device__ __forceinline__ void make_pa(const f32x16& s, Frag& lo, Frag& hi) {
  float p[16];
#pragma unroll
  for (int rg = 0; rg < 16; ++rg) p[rg] = fexp2(s[rg]);
  unsigned int a0 = cvtpk(p[0], p[1]),   b0 = cvtpk(p[4], p[5]);
  pl32swap(a0, b0);
  unsigned int a1 = cvtpk(p[2], p[3]),   b1 = cvtpk(p[6], p[7]);
  pl32swap(a1, b1);
  lo.u[0] = a0; lo.u[1] = a1; lo.u[2] = b0; lo.u[3] = b1;
  unsigned int c0 = cvtpk(p[8], p[9]),   d0 = cvtpk(p[12], p[13]);
  pl32swap(c0, d0);
  unsigned int c1 = cvtpk(p[10], p[11]), d1 = cvtpk(p[14], p[15]);
  pl32swap(c1, d1);
  hi.u[0] = c0; hi.u[1] = c1; hi.u[2] = d0; hi.u[3] = d1;
}

// ---------------------------------------------------------------------------
// Dual conv1x1 input stage via MFMA. blockIdx.z: 0 = theta(ref) -> Xnc (scaled
// by log2e) + Xcn; 1 = phi(cur) -> Ync only.
// ---------------------------------------------------------------------------
__global__ __launch_bounds__(256, 4) void nl_conv2m(
    const float* __restrict__ ref, const float* __restrict__ theta_w,
    const float* __restrict__ theta_b,
    const float* __restrict__ cur, const float* __restrict__ phi_w,
    const float* __restrict__ phi_b,
    unsigned short* __restrict__ Xnc, unsigned short* __restrict__ Xcn,
    unsigned short* __restrict__ Ync)
{
  __shared__ float sm[64 * 129];  // phase1: [c=128][j=64]; phase2: [j=64][o] stride 129
  const int z  = blockIdx.z;
  const float* in   = z ? cur : ref;
  const float* w    = z ? phi_w : theta_w;
  const float* bias = z ? phi_b : theta_b;
  unsigned short* out_nc = z ? Ync : Xnc;
  unsigned short* out_cn = z ? nullptr : Xcn;
  const float nc_scale = z ? 1.0f : LOG2E;

  const int b  = blockIdx.y;
  const int n0 = blockIdx.x * 64;
  const int t  = threadIdx.x;
  const int wave = t >> 6, lane = t & 63, q2 = lane >> 5, cm = lane & 31;

  // stage X fp32: [c][j], coalesced float2
#pragma unroll
  for (int k = 0; k < 16; ++k) {
    int flat = t + 256 * k;          // 4096 float2 slots
    int c = flat >> 5, jp = flat & 31;
    float2 v = *(const float2*)&in[(size_t)b * CC * NN + (size_t)c * NN + n0 + jp * 2];
    sm[c * 64 + jp * 2]     = v.x;
    sm[c * 64 + jp * 2 + 1] = v.y;
  }

  // A-frags: W rows o = wave*32 + cm, fp32 -> bf16
  bf16x8 wf[8];
  const int o0 = wave * 32 + cm;
#pragma unroll
  for (int k = 0; k < 8; ++k) {
    const float* wp = &w[o0 * CC + k * 16 + q2 * 8];
    float4 w0 = *(const float4*)wp, w1 = *(const float4*)(wp + 4);
    Frag f;
    f.u[0] = packbf(w0.x, w0.y); f.u[1] = packbf(w0.z, w0.w);
    f.u[2] = packbf(w1.x, w1.y); f.u[3] = packbf(w1.z, w1.w);
    wf[k] = f.v;
  }
  __syncthreads();

  // MFMA: per wave 2 j-tiles of 32; B-frag = 8 x ds_read_b32 (conflict-free) + cvtpk
  f32x16 acc[2];
  acc[0] = zero16(); acc[1] = zero16();
#pragma unroll
  for (int k = 0; k < 8; ++k) {
#pragma unroll
    for (int jt = 0; jt < 2; ++jt) {
      int base = (k * 16 + q2 * 8) * 64 + jt * 32 + cm;
      Frag xb;
      xb.u[0] = cvtpk(sm[base],       sm[base + 64]);
      xb.u[1] = cvtpk(sm[base + 128], sm[base + 192]);
      xb.u[2] = cvtpk(sm[base + 256], sm[base + 320]);
      xb.u[3] = cvtpk(sm[base + 384], sm[base + 448]);
      acc[jt] = __builtin_amdgcn_mfma_f32_32x32x16_bf16(wf[k], xb.v, acc[jt], 0, 0, 0);
    }
  }
  __syncthreads();  // all B-frag reads done; sm reusable

  // acc -> sm[j][129 o-stride] (+bias); D: col=j=jt*32+cm, row=o=wave*32+ROWPAT
#pragma unroll
  for (int jt = 0; jt < 2; ++jt)
#pragma unroll
    for (int rg = 0; rg < 16; ++rg) {
      int o = wave * 32 + ROWPAT(rg, q2);
      sm[(jt * 32 + cm) * 129 + o] = acc[jt][rg] + bias[o];
    }
  __syncthreads();

  // output stages (verbatim from proven conv2)
#pragma unroll
  for (int k = 0; k < 16; ++k) {
    int flat = t + 256 * k;           // [N][C] bf16 pairs
    int cp = flat & 63, jj = flat >> 6;
    float f0 = sm[jj * 129 + cp * 2] * nc_scale;
    float f1 = sm[jj * 129 + cp * 2 + 1] * nc_scale;
    *(unsigned int*)(out_nc + ((size_t)b * NN + n0 + jj) * CC + cp * 2) = packbf(f0, f1);
  }
  if (out_cn) {
#pragma unroll
    for (int k = 0; k < 16; ++k) {
      int flat = t + 256 * k;         // [C][N] bf16 n-pairs, unscaled
      int jp = flat & 31, c = flat >> 5;
      float f0 = sm[(jp * 2) * 129 + c], f1 = sm[(jp * 2 + 1) * 129 + c];
      *(unsigned int*)(out_cn + ((size_t)b * CC + c) * NN + n0 + jp * 2) = packbf(f0, f1);
    }
  }
}

// ---------------------------------------------------------------------------
// Pass 1: L[m] = sum_n exp2(s[n,m]) over an n-quarter. Double-buffered, 4
// blocks/CU. Xt swizzle ^(row&15): rows are 256B (0 mod 32 banks); &7 left
// lanes 8 apart colliding (4-way); &15 -> 2-way (free). [R10: worth ~7 us]
// ---------------------------------------------------------------------------
__global__ __launch_bounds__(256, 4) void nl_stats4(
    const unsigned short* __restrict__ Xnc, const unsigned short* __restrict__ Ync,
    float* __restrict__ Lpart)
{
  __shared__ unsigned short Xt[2][64 * 128];  // 2 x 16 KB, [n][c], chunk ^= (row&15)
  __shared__ float sL[2][2][2][32];           // [nh][mq][ct][cm]
  const int b = blockIdx.z, nq = blockIdx.y, mstrip = blockIdx.x;
  const int t = threadIdx.x;
  const int wave = t >> 6, lane = t & 63, q2 = lane >> 5, cm = lane & 31;
  const int mq = wave & 1, nh = wave >> 1;
  const int m0w = mstrip * 128 + mq * 64;

  bf16x8 bf[2][8];  // B[k=c][col=m] for 2 col-tiles of 32 m
#pragma unroll
  for (int ct = 0; ct < 2; ++ct)
#pragma unroll
    for (int k = 0; k < 8; ++k)
      bf[ct][k] = *(const bf16x8*)(Ync + ((size_t)b * NN + m0w + ct * 32 + cm) * CC + k * 16 + q2 * 8);

  // prologue: stage tile 0
  {
    const int n0 = nq * 1024;
#pragma unroll
    for (int i = 0; i < 4; ++i) {
      int slot = i * 256 + t;
      int row = slot >> 4, g = (slot & 15) ^ (row & 15);
      GLD16(Xnc + ((size_t)b * NN + n0 + row) * CC + g * 8, &Xt[0][0] + i * 2048 + wave * 512);
    }
  }

  float runL[2] = {0.f, 0.f};
#pragma unroll 2
  for (int nt = 0; nt < 16; ++nt) {
    __syncthreads();  // staging(nt) complete; buf^1 free (compute nt-1 done)
    if (nt < 15) {
      const int n0 = nq * 1024 + (nt + 1) * 64;
      unsigned short* dst = &Xt[(nt + 1) & 1][0];
#pragma unroll
      for (int i = 0; i < 4; ++i) {
        int slot = i * 256 + t;
        int row = slot >> 4, g = (slot & 15) ^ (row & 15);
        GLD16(Xnc + ((size_t)b * NN + n0 + row) * CC + g * 8, dst + i * 2048 + wave * 512);
      }
    }
    const unsigned short* src = &Xt[nt & 1][0];
    f32x16 acc0 = zero16(), acc1 = zero16();
#pragma unroll
    for (int k = 0; k < 8; ++k) {
      // read row = nh*32+cm -> row&15 = cm&15
      bf16x8 av = *(const bf16x8*)&src[(nh * 32 + cm) * 128 + (((k << 1) | q2) ^ (cm & 15)) * 8];
      acc0 = __builtin_amdgcn_mfma_f32_32x32x16_bf16(av, bf[0][k], acc0, 0, 0, 0);
      acc1 = __builtin_amdgcn_mfma_f32_32x32x16_bf16(av, bf[1][k], acc1, 0, 0, 0);
    }
#pragma unroll
    for (int rg = 0; rg < 16; ++rg) {
      runL[0] += fexp2(acc0[rg]);
      runL[1] += fexp2(acc1[rg]);
    }
  }
#pragma unroll
  for (int ct = 0; ct < 2; ++ct) runL[ct] += __shfl_xor(runL[ct], 32);
  if (q2 == 0) {
    sL[nh][mq][0][cm] = runL[0];
    sL[nh][mq][1][cm] = runL[1];
  }
  __syncthreads();
  if (t < 128) {
    int mq2 = t >> 6, ct2 = (t >> 5) & 1, cm2 = t & 31;
    float L = sL[0][mq2][ct2][cm2] + sL[1][mq2][ct2][cm2];
    Lpart[((size_t)nq * BB + b) * NN + mstrip * 128 + mq2 * 64 + ct2 * 32 + cm2] = L;
  }
}

// ---------------------------------------------------------------------------
// Fused mergeL + xscale: per (b, 64-m chunk): iL[m] = 1/sum(4 Lpart) in LDS,
// then Xcn[c][m] *= iL[m] in-place for all 128 c. Grid 512 = 2 blocks/CU.
// ---------------------------------------------------------------------------
__global__ __launch_bounds__(256) void nl_scalev(
    const float* __restrict__ Lp, unsigned short* __restrict__ Xcn)
{
  __shared__ float iL[64];
  const int b = blockIdx.y, mc = blockIdx.x;
  const int t = threadIdx.x;
  const int m0 = mc * 64;
  if (t < 64) {
    size_t idx = (size_t)b * NN + m0 + t;
    float L = Lp[idx] + Lp[(size_t)BB * NN + idx] + Lp[(size_t)2 * BB * NN + idx] +
              Lp[(size_t)3 * BB * NN + idx];
    iL[t] = 1.0f / L;
  }
  __syncthreads();
#pragma unroll
  for (int r = 0; r < 4; ++r) {
    int idx = r * 256 + t;            // 1024 groups of 8 bf16 (128 c x 8 mg)
    int c = idx >> 3, mg = idx & 7;
    size_t base = ((size_t)b * CC + c) * NN + m0 + mg * 8;
    Frag x; x.v = *(const bf16x8*)(Xcn + base);
    const float* il = &iL[mg * 8];
    Frag o;
    o.u[0] = packbf(bfu2f(x.u[0] & 0xffff) * il[0], bfu2f(x.u[0] >> 16) * il[1]);
    o.u[1] = packbf(bfu2f(x.u[1] & 0xffff) * il[2], bfu2f(x.u[1] >> 16) * il[3]);
    o.u[2] = packbf(bfu2f(x.u[2] & 0xffff) * il[4], bfu2f(x.u[2] >> 16) * il[5]);
    o.u[3] = packbf(bfu2f(x.u[3] & 0xffff) * il[6], bfu2f(x.u[3] >> 16) * il[7]);
    *(bf16x8*)(Xcn + base) = o.v;
  }
}

// ---------------------------------------------------------------------------
// Pass 2 (register-resident P; proven R9 structure = 76.5 us, VGPR 104):
// Zpart[n,c] = sum_m exp2(s[n,m])*Xsc[m,c] over an m-half. bf16 epilogue.
// R11 change: Yt swizzle upgraded ^(m&7) -> ^(m&15) on BOTH stage and read
// (rows 256B; av reads at rows cm and 32+cm share &15 = cm&15) — kills the
// av 4-way bank conflict. Xv (128B rows, 8 chunks) stays ^(c&7).
// [R10 lesson: paired-m z[2][4] acc spills at the 128-VGPR cap — dead end.]
// ---------------------------------------------------------------------------
__global__ __launch_bounds__(256, 2) void nl_pass2e2(
    const unsigned short* __restrict__ Xnc, const unsigned short* __restrict__ Ync,
    const unsigned short* __restrict__ Xsc,
    unsigned short* __restrict__ Zpart)
{
  __shared__ unsigned short Yt[2][64 * 128];  // [m][c], chunk ^= (m&15)
  __shared__ unsigned short Xv[2][128 * 64];  // [c][m], chunk ^= (c&7)
  const int b = blockIdx.z, mhalf = blockIdx.y, nstrip = blockIdx.x;
  const int t = threadIdx.x;
  const int wave = t >> 6, lane = t & 63, q2 = lane >> 5, cm = lane & 31;

  // X B-frags pinned: n cols = nstrip*128 + wave*32 + cm (whole kernel)
  bf16x8 af[8];
#pragma unroll
  for (int k = 0; k < 8; ++k)
    af[k] = *(const bf16x8*)(Xnc +
        ((size_t)b * NN + nstrip * 128 + wave * 32 + cm) * CC + k * 16 + q2 * 8);

  f32x16 z[4];
#pragma unroll
  for (int ct = 0; ct < 4; ++ct) z[ct] = zero16();

  // prologue: stage tile 0
  {
    const int m0g = mhalf * 2048;
#pragma unroll
    for (int i = 0; i < 4; ++i) {
      int slot = i * 256 + t;
      int row = slot >> 4, g = (slot & 15) ^ (row & 15);
      GLD16(Ync + ((size_t)b * NN + m0g + row) * CC + g * 8, &Yt[0][0] + i * 2048 + wave * 512);
    }
#pragma unroll
    for (int i = 0; i < 4; ++i) {
      int slot = i * 256 + t;
      int row = slot >> 3, g = (slot & 7) ^ (row & 7);
      GLD16(Xsc + ((size_t)b * CC + row) * NN + m0g + g * 8, &Xv[0][0] + i * 2048 + wave * 512);
    }
  }

#define P2_ITER(BUF, MT)                                                       \
  do {                                                                         \
    __syncthreads();                                                           \
    if ((MT) < 31) {                                                           \
      const int m0g = mhalf * 2048 + ((MT) + 1) * 64;                          \
      unsigned short* Yd = &Yt[(BUF) ^ 1][0];                                  \
      unsigned short* Xd = &Xv[(BUF) ^ 1][0];                                  \
      _Pragma("unroll")                                                        \
      for (int i = 0; i < 4; ++i) {                                            \
        int slot = i * 256 + t;                                                \
        int row = slot >> 4, g = (slot & 15) ^ (row & 15);                     \
        GLD16(Ync + ((size_t)b * NN + m0g + row) * CC + g * 8,                 \
              Yd + i * 2048 + wave * 512);                                     \
      }                                                                        \
      _Pragma("unroll")                                                        \
      for (int i = 0; i < 4; ++i) {                                            \
        int slot = i * 256 + t;                                                \
        int row = slot >> 3, g = (slot & 7) ^ (row & 7);                       \
        GLD16(Xsc + ((size_t)b * CC + row) * NN + m0g + g * 8,                 \
              Xd + i * 2048 + wave * 512);                                     \
      }                                                                        \
    }                                                                          \
    const unsigned short* Ys = &Yt[BUF][0];                                    \
    f32x16 s0 = zero16(), s1 = zero16();                                       \
    __builtin_amdgcn_s_setprio(1);                                             \
    _Pragma("unroll")                                                          \
    for (int k = 0; k < 8; ++k) {                                              \
      const int ch = (((k << 1) | q2) ^ (cm & 15)) * 8;                        \
      bf16x8 av0 = *(const bf16x8*)&Ys[cm * 128 + ch];                         \
      bf16x8 av1 = *(const bf16x8*)&Ys[(32 + cm) * 128 + ch];                  \
      s0 = __builtin_amdgcn_mfma_f32_32x32x16_bf16(av0, af[k], s0, 0, 0, 0);   \
      s1 = __builtin_amdgcn_mfma_f32_32x32x16_bf16(av1, af[k], s1, 0, 0, 0);   \
    }                                                                          \
    __builtin_amdgcn_s_setprio(0);                                             \
    Frag pa[4];                                                                \
    make_pa(s0, pa[0], pa[1]);                                                 \
    make_pa(s1, pa[2], pa[3]);                                                 \
    const unsigned short* Xs = &Xv[BUF][0];                                    \
    __builtin_amdgcn_s_setprio(1);                                             \
    _Pragma("unroll")                                                          \
    for (int ks = 0; ks < 4; ++ks) {                                           \
      const int ch = (((ks << 1) | q2) ^ (cm & 7)) * 8;                        \
      _Pragma("unroll")                                                        \
      for (int ct = 0; ct < 4; ++ct) {                                         \
        bf16x8 xv = *(const bf16x8*)&Xs[(ct * 32 + cm) * 64 + ch];             \
        z[ct] = __builtin_amdgcn_mfma_f32_32x32x16_bf16(pa[ks].v, xv, z[ct], 0, 0, 0); \
      }                                                                        \
    }                                                                          \
    __builtin_amdgcn_s_setprio(0);                                             \
  } while (0)

  for (int mt2 = 0; mt2 < 16; ++mt2) {
    P2_ITER(0, mt2 * 2);
    P2_ITER(1, mt2 * 2 + 1);
  }
#undef P2_ITER

  // epilogue: Zpart[mhalf][b][n][c] bf16
  unsigned short* Zp = Zpart + ((size_t)mhalf * BB + b) * NN * CC;
#pragma unroll
  for (int ct = 0; ct < 4; ++ct)
#pragma unroll
    for (int rg = 0; rg < 16; ++rg) {
      int n = nstrip * 128 + wave * 32 + ROWPAT(rg, q2);
      Zp[(size_t)n * CC + ct * 32 + cm] = f2bfu(z[ct][rg]);
    }
}

// ---------------------------------------------------------------------------
// Final conv1x1 via MFMA with fused Zpart reduction. 64-n strips (grid 512 =
// 2 blocks/CU) for latency hiding on the Zpart reads.
// ---------------------------------------------------------------------------
__global__ __launch_bounds__(256) void nl_convw2(
    const unsigned short* __restrict__ Zpart, const float* __restrict__ w,
    const float* __restrict__ bias, float* __restrict__ out)
{
  __shared__ unsigned short Zt[64 * 128];  // 16 KB, [n][c], chunk ^= (n&7)
  const int b = blockIdx.y, nstrip = blockIdx.x;  // 64 strips of 64 n
  const int t = threadIdx.x;
  const int wave = t >> 6, lane = t & 63, q2 = lane >> 5, cm = lane & 31;
  const int oh = wave & 1, nh2 = wave >> 1;       // o-half 64, n-half 32

  const unsigned short* Z0 = Zpart + ((size_t)b * NN + nstrip * 64) * CC;
  const unsigned short* Z1 = Z0 + (size_t)BB * NN * CC;
#pragma unroll
  for (int i = 0; i < 4; ++i) {
    int slot = i * 256 + t;
    int row = slot >> 4, g = slot & 15;
    size_t off = (size_t)row * CC + g * 8;
    Frag a, c2, o;
    a.v  = *(const bf16x8*)(Z0 + off);
    c2.v = *(const bf16x8*)(Z1 + off);
#pragma unroll
    for (int w2 = 0; w2 < 4; ++w2) {
      float lo = bfu2f((unsigned short)(a.u[w2] & 0xffff)) +
                 bfu2f((unsigned short)(c2.u[w2] & 0xffff));
      float hi = bfu2f((unsigned short)(a.u[w2] >> 16)) +
                 bfu2f((unsigned short)(c2.u[w2] >> 16));
      o.u[w2] = packbf(lo, hi);
    }
    *(bf16x8*)&Zt[row * 128 + ((g ^ (row & 7)) * 8)] = o.v;
  }

  // A-frags: W rows o = oh*64 + s2*32 + cm, fp32 -> bf16
  bf16x8 wf[2][8];
#pragma unroll
  for (int s2 = 0; s2 < 2; ++s2)
#pragma unroll
    for (int k = 0; k < 8; ++k) {
      const float* wp = &w[(oh * 64 + s2 * 32 + cm) * CC + k * 16 + q2 * 8];
      float4 w0 = *(const float4*)wp, w1 = *(const float4*)(wp + 4);
      Frag f;
      f.u[0] = packbf(w0.x, w0.y); f.u[1] = packbf(w0.z, w0.w);
      f.u[2] = packbf(w1.x, w1.y); f.u[3] = packbf(w1.z, w1.w);
      wf[s2][k] = f.v;
    }
  __syncthreads();

  f32x16 z[2];
  z[0] = zero16(); z[1] = zero16();
#pragma unroll
  for (int k = 0; k < 8; ++k) {
    bf16x8 bv = *(const bf16x8*)&Zt[(nh2 * 32 + cm) * 128 + (((k << 1) | q2) ^ (cm & 7)) * 8];
#pragma unroll
    for (int i = 0; i < 2; ++i)
      z[i] = __builtin_amdgcn_mfma_f32_32x32x16_bf16(wf[i][k], bv, z[i], 0, 0, 0);
  }

#pragma unroll
  for (int i = 0; i < 2; ++i)
#pragma unroll
    for (int rg = 0; rg < 16; ++rg) {
      int o = oh * 64 + i * 32 + ROWPAT(rg, q2);
      int n = nstrip * 64 + nh2 * 32 + cm;
      out[(size_t)b * CC * NN + (size_t)o * NN + n] = z[i][rg] + bias[o];
    }
}

// ---------------------------------------------------------------------------
extern "C" void kernel_launch(void* const* d_in, const int* in_sizes, int n_in,
                              void* d_out, int out_size, void* d_ws, size_t ws_size,
                              hipStream_t stream) {
  const float* cur     = (const float*)d_in[0];
  const float* ref     = (const float*)d_in[1];
  const float* theta_w = (const float*)d_in[2];
  const float* theta_b = (const float*)d_in[3];
  const float* phi_w   = (const float*)d_in[4];
  const float* phi_b   = (const float*)d_in[5];
  const float* Ww      = (const float*)d_in[6];
  const float* Wb      = (const float*)d_in[7];
  float* out = (float*)d_out;

  // ws: Xnc|Ync|Xcn bf16 (8MB ea) | Lpart 4*BB*NN f32 (0.5MB) | Zpart 2*BB*NN*CC bf16 (16MB)
  unsigned short* Xnc = (unsigned short*)d_ws;         // scaled by log2e
  unsigned short* Ync = Xnc + (size_t)BB * NN * CC;
  unsigned short* Xcn = Ync + (size_t)BB * NN * CC;    // becomes Xsc in-place
  float* Lpart = (float*)(Xcn + (size_t)BB * NN * CC);
  unsigned short* Zpart = (unsigned short*)(Lpart + (size_t)4 * BB * NN);

  dim3 blk(256);
  nl_conv2m  <<<dim3(64, BB, 2), blk, 0, stream>>>(ref, theta_w, theta_b,
                                                   cur, phi_w, phi_b, Xnc, Xcn, Ync);
  nl_stats4  <<<dim3(32, 4, BB), blk, 0, stream>>>(Xnc, Ync, Lpart);
  nl_scalev  <<<dim3(64, BB), blk, 0, stream>>>(Lpart, Xcn);
  nl_pass2e2 <<<dim3(32, 2, BB), blk, 0, stream>>>(Xnc, Ync, Xcn, Zpart);
  nl_convw2  <<<dim3(64, BB), blk, 0, stream>>>(Zpart, Ww, Wb, out);
}

// Round 12
// 230.970 us; speedup vs baseline: 1.4514x; 1.0101x over previous
//
#include <hip/hip_runtime.h>
#include <hip/hip_bf16.h>

#define BB 8
#define CC 128
#define NN 4096  // H*W
#define LOG2E 1.44269504088896340736f

typedef __attribute__((ext_vector_type(8))) short bf16x8;   // 8 bf16 = 4 VGPRs
typedef __attribute__((ext_vector_type(16))) float f32x16;

static __device__ __forceinline__ unsigned short f2bfu(float f) {
  unsigned int x = __float_as_uint(f);
  x += 0x7fffu + ((x >> 16) & 1u);
  return (unsigned short)(x >> 16);
}
static __device__ __forceinline__ unsigned int packbf(float a, float b) {
  return (unsigned int)f2bfu(a) | ((unsigned int)f2bfu(b) << 16);
}
static __device__ __forceinline__ float bfu2f(unsigned short u) {
  return __uint_as_float((unsigned int)u << 16);
}
// raw v_exp_f32 (2^x). Domain bounded (|s|<90) -> no range fixup needed.
static __device__ __forceinline__ float fexp2(float x) {
  return __builtin_amdgcn_exp2f(x);
}
static __device__ __forceinline__ f32x16 zero16() {
  f32x16 z;
#pragma unroll
  for (int i = 0; i < 16; ++i) z[i] = 0.f;
  return z;
}
union Frag { int i[4]; unsigned int u[4]; bf16x8 v; };

// RNE pack of two f32 -> two bf16 in one dword (lo = a). No builtin on gfx950.
static __device__ __forceinline__ unsigned int cvtpk(float a, float b) {
  unsigned int r;
  asm("v_cvt_pk_bf16_f32 %0, %1, %2" : "=v"(r) : "v"(a), "v"(b));
  return r;
}
// Swap d[lanes 32..63] <-> s[lanes 0..31]; both results used.
static __device__ __forceinline__ void pl32swap(unsigned int& d, unsigned int& s) {
  asm volatile("v_permlane32_swap_b32 %0, %1" : "+v"(d), "+v"(s));
}

// async global->LDS, 16B/lane; LDS dest = wave-uniform base + lane*16.
#define GLD16(gp, lp)                                                     \
  __builtin_amdgcn_global_load_lds(                                       \
      (const __attribute__((address_space(1))) unsigned int*)(gp),        \
      (__attribute__((address_space(3))) unsigned int*)(lp), 16, 0, 0)

// C/D row pattern for 32x32 MFMA: row = (rg&3) + 8*(rg>>2) + 4*q2
#define ROWPAT(rg, q2) (((rg) & 3) + 8 * ((rg) >> 2) + 4 * (q2))

// Build 2 PV A-frags from a 32-row S' acc, scaling by iL[m] (softmax denom
// folded into P instead of pre-scaling X — R12). lane holds
// p[rg] = P[m = ROWPAT(rg,q2)][n = cm] * iL[m]; rows for rg-group j are
// 4q2+8j+0..3 (consecutive) -> 4 float4 LDS reads, 2 distinct addrs/wave
// (broadcast). A-frag lo/hi as in the verified R0/R1 recipe.
static __device__ __forceinline__ void make_pa_s(
    const f32x16& s, const float* il, int q2, Frag& lo, Frag& hi) {
  const float4 i0 = *(const float4*)&il[4 * q2];
  const float4 i1 = *(const float4*)&il[4 * q2 + 8];
  const float4 i2 = *(const float4*)&il[4 * q2 + 16];
  const float4 i3 = *(const float4*)&il[4 * q2 + 24];
  float p[16];
  p[0]  = fexp2(s[0])  * i0.x; p[1]  = fexp2(s[1])  * i0.y;
  p[2]  = fexp2(s[2])  * i0.z; p[3]  = fexp2(s[3])  * i0.w;
  p[4]  = fexp2(s[4])  * i1.x; p[5]  = fexp2(s[5])  * i1.y;
  p[6]  = fexp2(s[6])  * i1.z; p[7]  = fexp2(s[7])  * i1.w;
  p[8]  = fexp2(s[8])  * i2.x; p[9]  = fexp2(s[9])  * i2.y;
  p[10] = fexp2(s[10]) * i2.z; p[11] = fexp2(s[11]) * i2.w;
  p[12] = fexp2(s[12]) * i3.x; p[13] = fexp2(s[13]) * i3.y;
  p[14] = fexp2(s[14]) * i3.z; p[15] = fexp2(s[15]) * i3.w;
  unsigned int a0 = cvtpk(p[0], p[1]),   b0 = cvtpk(p[4], p[5]);
  pl32swap(a0, b0);
  unsigned int a1 = cvtpk(p[2], p[3]),   b1 = cvtpk(p[6], p[7]);
  pl32swap(a1, b1);
  lo.u[0] = a0; lo.u[1] = a1; lo.u[2] = b0; lo.u[3] = b1;
  unsigned int c0 = cvtpk(p[8], p[9]),   d0 = cvtpk(p[12], p[13]);
  pl32swap(c0, d0);
  unsigned int c1 = cvtpk(p[10], p[11]), d1 = cvtpk(p[14], p[15]);
  pl32swap(c1, d1);
  hi.u[0] = c0; hi.u[1] = c1; hi.u[2] = d0; hi.u[3] = d1;
}

// ---------------------------------------------------------------------------
// Dual conv1x1 input stage via MFMA. blockIdx.z: 0 = theta(ref) -> Xnc (scaled
// by log2e) + Xcn; 1 = phi(cur) -> Ync only.
// ---------------------------------------------------------------------------
__global__ __launch_bounds__(256, 4) void nl_conv2m(
    const float* __restrict__ ref, const float* __restrict__ theta_w,
    const float* __restrict__ theta_b,
    const float* __restrict__ cur, const float* __restrict__ phi_w,
    const float* __restrict__ phi_b,
    unsigned short* __restrict__ Xnc, unsigned short* __restrict__ Xcn,
    unsigned short* __restrict__ Ync)
{
  __shared__ float sm[64 * 129];  // phase1: [c=128][j=64]; phase2: [j=64][o] stride 129
  const int z  = blockIdx.z;
  const float* in   = z ? cur : ref;
  const float* w    = z ? phi_w : theta_w;
  const float* bias = z ? phi_b : theta_b;
  unsigned short* out_nc = z ? Ync : Xnc;
  unsigned short* out_cn = z ? nullptr : Xcn;
  const float nc_scale = z ? 1.0f : LOG2E;

  const int b  = blockIdx.y;
  const int n0 = blockIdx.x * 64;
  const int t  = threadIdx.x;
  const int wave = t >> 6, lane = t & 63, q2 = lane >> 5, cm = lane & 31;

  // stage X fp32: [c][j], coalesced float2
#pragma unroll
  for (int k = 0; k < 16; ++k) {
    int flat = t + 256 * k;          // 4096 float2 slots
    int c = flat >> 5, jp = flat & 31;
    float2 v = *(const float2*)&in[(size_t)b * CC * NN + (size_t)c * NN + n0 + jp * 2];
    sm[c * 64 + jp * 2]     = v.x;
    sm[c * 64 + jp * 2 + 1] = v.y;
  }

  // A-frags: W rows o = wave*32 + cm, fp32 -> bf16
  bf16x8 wf[8];
  const int o0 = wave * 32 + cm;
#pragma unroll
  for (int k = 0; k < 8; ++k) {
    const float* wp = &w[o0 * CC + k * 16 + q2 * 8];
    float4 w0 = *(const float4*)wp, w1 = *(const float4*)(wp + 4);
    Frag f;
    f.u[0] = packbf(w0.x, w0.y); f.u[1] = packbf(w0.z, w0.w);
    f.u[2] = packbf(w1.x, w1.y); f.u[3] = packbf(w1.z, w1.w);
    wf[k] = f.v;
  }
  __syncthreads();

  // MFMA: per wave 2 j-tiles of 32; B-frag = 8 x ds_read_b32 (conflict-free) + cvtpk
  f32x16 acc[2];
  acc[0] = zero16(); acc[1] = zero16();
#pragma unroll
  for (int k = 0; k < 8; ++k) {
#pragma unroll
    for (int jt = 0; jt < 2; ++jt) {
      int base = (k * 16 + q2 * 8) * 64 + jt * 32 + cm;
      Frag xb;
      xb.u[0] = cvtpk(sm[base],       sm[base + 64]);
      xb.u[1] = cvtpk(sm[base + 128], sm[base + 192]);
      xb.u[2] = cvtpk(sm[base + 256], sm[base + 320]);
      xb.u[3] = cvtpk(sm[base + 384], sm[base + 448]);
      acc[jt] = __builtin_amdgcn_mfma_f32_32x32x16_bf16(wf[k], xb.v, acc[jt], 0, 0, 0);
    }
  }
  __syncthreads();  // all B-frag reads done; sm reusable

  // acc -> sm[j][129 o-stride] (+bias); D: col=j=jt*32+cm, row=o=wave*32+ROWPAT
#pragma unroll
  for (int jt = 0; jt < 2; ++jt)
#pragma unroll
    for (int rg = 0; rg < 16; ++rg) {
      int o = wave * 32 + ROWPAT(rg, q2);
      sm[(jt * 32 + cm) * 129 + o] = acc[jt][rg] + bias[o];
    }
  __syncthreads();

  // output stages (verbatim from proven conv2)
#pragma unroll
  for (int k = 0; k < 16; ++k) {
    int flat = t + 256 * k;           // [N][C] bf16 pairs
    int cp = flat & 63, jj = flat >> 6;
    float f0 = sm[jj * 129 + cp * 2] * nc_scale;
    float f1 = sm[jj * 129 + cp * 2 + 1] * nc_scale;
    *(unsigned int*)(out_nc + ((size_t)b * NN + n0 + jj) * CC + cp * 2) = packbf(f0, f1);
  }
  if (out_cn) {
#pragma unroll
    for (int k = 0; k < 16; ++k) {
      int flat = t + 256 * k;         // [C][N] bf16 n-pairs, unscaled
      int jp = flat & 31, c = flat >> 5;
      float f0 = sm[(jp * 2) * 129 + c], f1 = sm[(jp * 2 + 1) * 129 + c];
      *(unsigned int*)(out_cn + ((size_t)b * CC + c) * NN + n0 + jp * 2) = packbf(f0, f1);
    }
  }
}

// ---------------------------------------------------------------------------
// Pass 1: L[m] = sum_n exp2(s[n,m]) over an n-quarter. Double-buffered, 4
// blocks/CU. Xt swizzle ^(row&15) (R10: worth ~7 us vs &7).
// ---------------------------------------------------------------------------
__global__ __launch_bounds__(256, 4) void nl_stats4(
    const unsigned short* __restrict__ Xnc, const unsigned short* __restrict__ Ync,
    float* __restrict__ Lpart)
{
  __shared__ unsigned short Xt[2][64 * 128];  // 2 x 16 KB, [n][c], chunk ^= (row&15)
  __shared__ float sL[2][2][2][32];           // [nh][mq][ct][cm]
  const int b = blockIdx.z, nq = blockIdx.y, mstrip = blockIdx.x;
  const int t = threadIdx.x;
  const int wave = t >> 6, lane = t & 63, q2 = lane >> 5, cm = lane & 31;
  const int mq = wave & 1, nh = wave >> 1;
  const int m0w = mstrip * 128 + mq * 64;

  bf16x8 bf[2][8];  // B[k=c][col=m] for 2 col-tiles of 32 m
#pragma unroll
  for (int ct = 0; ct < 2; ++ct)
#pragma unroll
    for (int k = 0; k < 8; ++k)
      bf[ct][k] = *(const bf16x8*)(Ync + ((size_t)b * NN + m0w + ct * 32 + cm) * CC + k * 16 + q2 * 8);

  // prologue: stage tile 0
  {
    const int n0 = nq * 1024;
#pragma unroll
    for (int i = 0; i < 4; ++i) {
      int slot = i * 256 + t;
      int row = slot >> 4, g = (slot & 15) ^ (row & 15);
      GLD16(Xnc + ((size_t)b * NN + n0 + row) * CC + g * 8, &Xt[0][0] + i * 2048 + wave * 512);
    }
  }

  float runL[2] = {0.f, 0.f};
#pragma unroll 2
  for (int nt = 0; nt < 16; ++nt) {
    __syncthreads();  // staging(nt) complete; buf^1 free (compute nt-1 done)
    if (nt < 15) {
      const int n0 = nq * 1024 + (nt + 1) * 64;
      unsigned short* dst = &Xt[(nt + 1) & 1][0];
#pragma unroll
      for (int i = 0; i < 4; ++i) {
        int slot = i * 256 + t;
        int row = slot >> 4, g = (slot & 15) ^ (row & 15);
        GLD16(Xnc + ((size_t)b * NN + n0 + row) * CC + g * 8, dst + i * 2048 + wave * 512);
      }
    }
    const unsigned short* src = &Xt[nt & 1][0];
    f32x16 acc0 = zero16(), acc1 = zero16();
#pragma unroll
    for (int k = 0; k < 8; ++k) {
      // read row = nh*32+cm -> row&15 = cm&15
      bf16x8 av = *(const bf16x8*)&src[(nh * 32 + cm) * 128 + (((k << 1) | q2) ^ (cm & 15)) * 8];
      acc0 = __builtin_amdgcn_mfma_f32_32x32x16_bf16(av, bf[0][k], acc0, 0, 0, 0);
      acc1 = __builtin_amdgcn_mfma_f32_32x32x16_bf16(av, bf[1][k], acc1, 0, 0, 0);
    }
#pragma unroll
    for (int rg = 0; rg < 16; ++rg) {
      runL[0] += fexp2(acc0[rg]);
      runL[1] += fexp2(acc1[rg]);
    }
  }
#pragma unroll
  for (int ct = 0; ct < 2; ++ct) runL[ct] += __shfl_xor(runL[ct], 32);
  if (q2 == 0) {
    sL[nh][mq][0][cm] = runL[0];
    sL[nh][mq][1][cm] = runL[1];
  }
  __syncthreads();
  if (t < 128) {
    int mq2 = t >> 6, ct2 = (t >> 5) & 1, cm2 = t & 31;
    float L = sL[0][mq2][ct2][cm2] + sL[1][mq2][ct2][cm2];
    Lpart[((size_t)nq * BB + b) * NN + mstrip * 128 + mq2 * 64 + ct2 * 32 + cm2] = L;
  }
}

// ---------------------------------------------------------------------------
// Pass 2 (register-resident P, iL folded into P — R12): Zpart[n,c] =
// sum_m exp2(s[n,m])*iL[m]*X[m,c] over an m-half. Replaces the separate
// scalev kernel (16 MB r/w + launch gap). iLs[2048] staged in LDS at
// prologue (block's m-half), consumed in make_pa_s. LDS 72 KB, 2 blocks/CU.
// Yt swizzle ^(m&15) (R11, conflicts halved); Xv ^(c&7) (structural floor).
// ---------------------------------------------------------------------------
__global__ __launch_bounds__(256, 2) void nl_pass2e3(
    const unsigned short* __restrict__ Xnc, const unsigned short* __restrict__ Ync,
    const unsigned short* __restrict__ Xcn, const float* __restrict__ Lpart,
    unsigned short* __restrict__ Zpart)
{
  __shared__ unsigned short Yt[2][64 * 128];  // [m][c], chunk ^= (m&15)
  __shared__ unsigned short Xv[2][128 * 64];  // [c][m], chunk ^= (c&7)
  __shared__ float iLs[2048];                 // 1/L for the block's m-half
  const int b = blockIdx.z, mhalf = blockIdx.y, nstrip = blockIdx.x;
  const int t = threadIdx.x;
  const int wave = t >> 6, lane = t & 63, q2 = lane >> 5, cm = lane & 31;

  // X B-frags pinned: n cols = nstrip*128 + wave*32 + cm (whole kernel)
  bf16x8 af[8];
#pragma unroll
  for (int k = 0; k < 8; ++k)
    af[k] = *(const bf16x8*)(Xnc +
        ((size_t)b * NN + nstrip * 128 + wave * 32 + cm) * CC + k * 16 + q2 * 8);

  f32x16 z[4];
#pragma unroll
  for (int ct = 0; ct < 4; ++ct) z[ct] = zero16();

  // prologue: stage tile 0 + compute iLs (covered by first loop barrier)
  {
    const int m0g = mhalf * 2048;
#pragma unroll
    for (int i = 0; i < 4; ++i) {
      int slot = i * 256 + t;
      int row = slot >> 4, g = (slot & 15) ^ (row & 15);
      GLD16(Ync + ((size_t)b * NN + m0g + row) * CC + g * 8, &Yt[0][0] + i * 2048 + wave * 512);
    }
#pragma unroll
    for (int i = 0; i < 4; ++i) {
      int slot = i * 256 + t;
      int row = slot >> 3, g = (slot & 7) ^ (row & 7);
      GLD16(Xcn + ((size_t)b * CC + row) * NN + m0g + g * 8, &Xv[0][0] + i * 2048 + wave * 512);
    }
    const float* Lp0 = Lpart + (size_t)b * NN + m0g;
#pragma unroll
    for (int i = 0; i < 8; ++i) {
      int ml = i * 256 + t;
      float L = Lp0[ml] + Lp0[(size_t)BB * NN + ml] +
                Lp0[(size_t)2 * BB * NN + ml] + Lp0[(size_t)3 * BB * NN + ml];
      iLs[ml] = 1.0f / L;
    }
  }

#define P2_ITER(BUF, MT)                                                       \
  do {                                                                         \
    __syncthreads();                                                           \
    if ((MT) < 31) {                                                           \
      const int m0g = mhalf * 2048 + ((MT) + 1) * 64;                          \
      unsigned short* Yd = &Yt[(BUF) ^ 1][0];                                  \
      unsigned short* Xd = &Xv[(BUF) ^ 1][0];                                  \
      _Pragma("unroll")                                                        \
      for (int i = 0; i < 4; ++i) {                                            \
        int slot = i * 256 + t;                                                \
        int row = slot >> 4, g = (slot & 15) ^ (row & 15);                     \
        GLD16(Ync + ((size_t)b * NN + m0g + row) * CC + g * 8,                 \
              Yd + i * 2048 + wave * 512);                                     \
      }                                                                        \
      _Pragma("unroll")                                                        \
      for (int i = 0; i < 4; ++i) {                                            \
        int slot = i * 256 + t;                                                \
        int row = slot >> 3, g = (slot & 7) ^ (row & 7);                       \
        GLD16(Xcn + ((size_t)b * CC + row) * NN + m0g + g * 8,                 \
              Xd + i * 2048 + wave * 512);                                     \
      }                                                                        \
    }                                                                          \
    const unsigned short* Ys = &Yt[BUF][0];                                    \
    f32x16 s0 = zero16(), s1 = zero16();                                       \
    __builtin_amdgcn_s_setprio(1);                                             \
    _Pragma("unroll")                                                          \
    for (int k = 0; k < 8; ++k) {                                              \
      const int ch = (((k << 1) | q2) ^ (cm & 15)) * 8;                        \
      bf16x8 av0 = *(const bf16x8*)&Ys[cm * 128 + ch];                         \
      bf16x8 av1 = *(const bf16x8*)&Ys[(32 + cm) * 128 + ch];                  \
      s0 = __builtin_amdgcn_mfma_f32_32x32x16_bf16(av0, af[k], s0, 0, 0, 0);   \
      s1 = __builtin_amdgcn_mfma_f32_32x32x16_bf16(av1, af[k], s1, 0, 0, 0);   \
    }                                                                          \
    __builtin_amdgcn_s_setprio(0);                                             \
    Frag pa[4];                                                                \
    make_pa_s(s0, &iLs[(MT) * 64],      q2, pa[0], pa[1]);                     \
    make_pa_s(s1, &iLs[(MT) * 64 + 32], q2, pa[2], pa[3]);                     \
    const unsigned short* Xs = &Xv[BUF][0];                                    \
    __builtin_amdgcn_s_setprio(1);                                             \
    _Pragma("unroll")                                                          \
    for (int ks = 0; ks < 4; ++ks) {                                           \
      const int ch = (((ks << 1) | q2) ^ (cm & 7)) * 8;                        \
      _Pragma("unroll")                                                        \
      for (int ct = 0; ct < 4; ++ct) {                                         \
        bf16x8 xv = *(const bf16x8*)&Xs[(ct * 32 + cm) * 64 + ch];             \
        z[ct] = __builtin_amdgcn_mfma_f32_32x32x16_bf16(pa[ks].v, xv, z[ct], 0, 0, 0); \
      }                                                                        \
    }                                                                          \
    __builtin_amdgcn_s_setprio(0);                                             \
  } while (0)

  for (int mt2 = 0; mt2 < 16; ++mt2) {
    P2_ITER(0, mt2 * 2);
    P2_ITER(1, mt2 * 2 + 1);
  }
#undef P2_ITER

  // epilogue: Zpart[mhalf][b][n][c] bf16
  unsigned short* Zp = Zpart + ((size_t)mhalf * BB + b) * NN * CC;
#pragma unroll
  for (int ct = 0; ct < 4; ++ct)
#pragma unroll
    for (int rg = 0; rg < 16; ++rg) {
      int n = nstrip * 128 + wave * 32 + ROWPAT(rg, q2);
      Zp[(size_t)n * CC + ct * 32 + cm] = f2bfu(z[ct][rg]);
    }
}

// ---------------------------------------------------------------------------
// Final conv1x1 via MFMA with fused Zpart reduction. 64-n strips (grid 512 =
// 2 blocks/CU). Zt swizzle ^(&15) (256B rows — mirrors stats4/pass2 fix).
// ---------------------------------------------------------------------------
__global__ __launch_bounds__(256) void nl_convw2(
    const unsigned short* __restrict__ Zpart, const float* __restrict__ w,
    const float* __restrict__ bias, float* __restrict__ out)
{
  __shared__ unsigned short Zt[64 * 128];  // 16 KB, [n][c], chunk ^= (n&15)
  const int b = blockIdx.y, nstrip = blockIdx.x;  // 64 strips of 64 n
  const int t = threadIdx.x;
  const int wave = t >> 6, lane = t & 63, q2 = lane >> 5, cm = lane & 31;
  const int oh = wave & 1, nh2 = wave >> 1;       // o-half 64, n-half 32

  const unsigned short* Z0 = Zpart + ((size_t)b * NN + nstrip * 64) * CC;
  const unsigned short* Z1 = Z0 + (size_t)BB * NN * CC;
#pragma unroll
  for (int i = 0; i < 4; ++i) {
    int slot = i * 256 + t;
    int row = slot >> 4, g = slot & 15;
    size_t off = (size_t)row * CC + g * 8;
    Frag a, c2, o;
    a.v  = *(const bf16x8*)(Z0 + off);
    c2.v = *(const bf16x8*)(Z1 + off);
#pragma unroll
    for (int w2 = 0; w2 < 4; ++w2) {
      float lo = bfu2f((unsigned short)(a.u[w2] & 0xffff)) +
                 bfu2f((unsigned short)(c2.u[w2] & 0xffff));
      float hi = bfu2f((unsigned short)(a.u[w2] >> 16)) +
                 bfu2f((unsigned short)(c2.u[w2] >> 16));
      o.u[w2] = packbf(lo, hi);
    }
    *(bf16x8*)&Zt[row * 128 + ((g ^ (row & 15)) * 8)] = o.v;
  }

  // A-frags: W rows o = oh*64 + s2*32 + cm, fp32 -> bf16
  bf16x8 wf[2][8];
#pragma unroll
  for (int s2 = 0; s2 < 2; ++s2)
#pragma unroll
    for (int k = 0; k < 8; ++k) {
      const float* wp = &w[(oh * 64 + s2 * 32 + cm) * CC + k * 16 + q2 * 8];
      float4 w0 = *(const float4*)wp, w1 = *(const float4*)(wp + 4);
      Frag f;
      f.u[0] = packbf(w0.x, w0.y); f.u[1] = packbf(w0.z, w0.w);
      f.u[2] = packbf(w1.x, w1.y); f.u[3] = packbf(w1.z, w1.w);
      wf[s2][k] = f.v;
    }
  __syncthreads();

  f32x16 z[2];
  z[0] = zero16(); z[1] = zero16();
#pragma unroll
  for (int k = 0; k < 8; ++k) {
    // read row = nh2*32+cm -> row&15 = cm&15
    bf16x8 bv = *(const bf16x8*)&Zt[(nh2 * 32 + cm) * 128 + (((k << 1) | q2) ^ (cm & 15)) * 8];
#pragma unroll
    for (int i = 0; i < 2; ++i)
      z[i] = __builtin_amdgcn_mfma_f32_32x32x16_bf16(wf[i][k], bv, z[i], 0, 0, 0);
  }

#pragma unroll
  for (int i = 0; i < 2; ++i)
#pragma unroll
    for (int rg = 0; rg < 16; ++rg) {
      int o = oh * 64 + i * 32 + ROWPAT(rg, q2);
      int n = nstrip * 64 + nh2 * 32 + cm;
      out[(size_t)b * CC * NN + (size_t)o * NN + n] = z[i][rg] + bias[o];
    }
}

// ---------------------------------------------------------------------------
extern "C" void kernel_launch(void* const* d_in, const int* in_sizes, int n_in,
                              void* d_out, int out_size, void* d_ws, size_t ws_size,
                              hipStream_t stream) {
  const float* cur     = (const float*)d_in[0];
  const float* ref     = (const float*)d_in[1];
  const float* theta_w = (const float*)d_in[2];
  const float* theta_b = (const float*)d_in[3];
  const float* phi_w   = (const float*)d_in[4];
  const float* phi_b   = (const float*)d_in[5];
  const float* Ww      = (const float*)d_in[6];
  const float* Wb      = (const float*)d_in[7];
  float* out = (float*)d_out;

  // ws: Xnc|Ync|Xcn bf16 (8MB ea) | Lpart 4*BB*NN f32 (0.5MB) | Zpart 2*BB*NN*CC bf16 (16MB)
  unsigned short* Xnc = (unsigned short*)d_ws;         // scaled by log2e
  unsigned short* Ync = Xnc + (size_t)BB * NN * CC;
  unsigned short* Xcn = Ync + (size_t)BB * NN * CC;    // unscaled theta(ref) [C][N]
  float* Lpart = (float*)(Xcn + (size_t)BB * NN * CC);
  unsigned short* Zpart = (unsigned short*)(Lpart + (size_t)4 * BB * NN);

  dim3 blk(256);
  nl_conv2m  <<<dim3(64, BB, 2), blk, 0, stream>>>(ref, theta_w, theta_b,
                                                   cur, phi_w, phi_b, Xnc, Xcn, Ync);
  nl_stats4  <<<dim3(32, 4, BB), blk, 0, stream>>>(Xnc, Ync, Lpart);
  nl_pass2e3 <<<dim3(32, 2, BB), blk, 0, stream>>>(Xnc, Ync, Xcn, Lpart, Zpart);
  nl_convw2  <<<dim3(64, BB), blk, 0, stream>>>(Zpart, Ww, Wb, out);
}